// Round 1
// baseline (165.432 us; speedup 1.0000x reference)
//
#include <hip/hip_runtime.h>
#include <hip/hip_bf16.h>
#include <stdint.h>

#define BB   2
#define NN   2048
#define BN   (BB*NN)
#define KTOP 48
#define EIN  416
#define EF   128
#define LROW 424   // padded feature row length in ushorts (16B-aligned rows, low bank conflict)

typedef __attribute__((ext_vector_type(8))) short s8v;
typedef __attribute__((ext_vector_type(4))) float f32x4;
typedef unsigned short u16;
typedef unsigned int u32;
typedef unsigned long long u64;

__device__ __constant__ int cPA[25] = {1,0,2,3,4,1,1,1,1,0,0,0,4,4,3,0,2,3,4,2,3,4,2,3,2};
__device__ __constant__ int cPB[25] = {1,0,2,3,4,0,2,3,4,2,3,4,2,3,2,1,1,1,1,0,0,0,4,4,3};

__device__ __forceinline__ u16 bf16u(float x) {
  __hip_bfloat16 h = __float2bfloat16(x);
  return *reinterpret_cast<u16*>(&h);
}

// ---------------- prep: atoms5 (N,Ca,C,O,Cb), packed Ca, W_edge^T in bf16 ----------------
__global__ __launch_bounds__(256) void prep_kernel(const float* __restrict__ X,
                                                   const float* __restrict__ W_edge,
                                                   float* __restrict__ atoms5,
                                                   float* __restrict__ capack,
                                                   u16* __restrict__ wt) {
  int tid = blockIdx.x * 256 + threadIdx.x;
  if (tid < EIN * EF) {
    // W_edge is [416][128]; wt is [128][416] bf16
    int n = tid & (EF - 1), kk = tid >> 7;
    wt[(size_t)n * EIN + kk] = bf16u(W_edge[tid]);
  } else if (tid < EIN * EF + BN) {
    int idx = tid - EIN * EF;
    const float* x = X + (size_t)idx * 12;
    float Nx = x[0], Ny = x[1], Nz = x[2];
    float Cax = x[3], Cay = x[4], Caz = x[5];
    float Cx = x[6], Cy = x[7], Cz = x[8];
    float Ox = x[9], Oy = x[10], Oz = x[11];
    float bx = Cax - Nx, by = Cay - Ny, bz = Caz - Nz;
    float cx = Cx - Cax, cy = Cy - Cay, cz = Cz - Caz;
    float ax = by * cz - bz * cy;
    float ay = bz * cx - bx * cz;
    float az = bx * cy - by * cx;
    float Cbx = -0.58273431f * ax + 0.56802827f * bx - 0.54067466f * cx + Cax;
    float Cby = -0.58273431f * ay + 0.56802827f * by - 0.54067466f * cy + Cay;
    float Cbz = -0.58273431f * az + 0.56802827f * bz - 0.54067466f * cz + Caz;
    float* o = atoms5 + (size_t)idx * 15;
    o[0] = Nx;  o[1] = Ny;  o[2] = Nz;
    o[3] = Cax; o[4] = Cay; o[5] = Caz;
    o[6] = Cx;  o[7] = Cy;  o[8] = Cz;
    o[9] = Ox;  o[10] = Oy; o[11] = Oz;
    o[12] = Cbx; o[13] = Cby; o[14] = Cbz;
    capack[idx * 3 + 0] = Cax;
    capack[idx * 3 + 1] = Cay;
    capack[idx * 3 + 2] = Caz;
  }
}

// ---------------- top-48 per row: one wave per row, keys in registers ----------------
__global__ __launch_bounds__(64) void topk_kernel(const float* __restrict__ capack,
                                                  const float* __restrict__ mask,
                                                  int* __restrict__ eidx,
                                                  float* __restrict__ dtop,
                                                  float* __restrict__ eidx_f) {
  int row = blockIdx.x;            // 0..BN-1
  int b = row >> 11, i = row & (NN - 1);
  int lane = threadIdx.x;
  const float* cab = capack + (size_t)b * NN * 3;
  const float* mrow = mask + (size_t)b * NN;
  float cix = cab[i * 3 + 0], ciy = cab[i * 3 + 1], ciz = cab[i * 3 + 2];
  float mi = mrow[i];

  float dv[32];
  float m2v[32];
  float rmax = -1.0f;
#pragma unroll
  for (int s = 0; s < 32; ++s) {
    int j = s * 64 + lane;
    float dx = cix - cab[j * 3 + 0];
    float dy = ciy - cab[j * 3 + 1];
    float dz = ciz - cab[j * 3 + 2];
    float d = sqrtf(dx * dx + dy * dy + dz * dz + 1e-6f);
    float m2 = mi * mrow[j];
    float D = m2 * d;
    dv[s] = D;
    m2v[s] = m2;
    rmax = fmaxf(rmax, D);
  }
#pragma unroll
  for (int off = 32; off >= 1; off >>= 1)
    rmax = fmaxf(rmax, __shfl_xor(rmax, off));
#pragma unroll
  for (int s = 0; s < 32; ++s)
    dv[s] = dv[s] + (1.0f - m2v[s]) * rmax;

  float bestv = 3.4e38f;
  int bests = 0;
#pragma unroll
  for (int s = 0; s < 32; ++s)
    if (dv[s] < bestv) { bestv = dv[s]; bests = s; }

  unsigned removed = 0;
  for (int k = 0; k < KTOP; ++k) {
    u64 key = ((u64)__float_as_uint(bestv) << 32) | (u32)(bests * 64 + lane);
#pragma unroll
    for (int off = 32; off >= 1; off >>= 1) {
      u64 o = __shfl_xor(key, off);
      key = (o < key) ? o : key;
    }
    u32 jwin = (u32)(key & 0xffffffffull);
    if (lane == 0) {
      eidx[row * KTOP + k] = (int)jwin;
      eidx_f[row * KTOP + k] = (float)jwin;
      dtop[row * KTOP + k] = __uint_as_float((u32)(key >> 32));
    }
    if (lane == (int)(jwin & 63u)) {
      removed |= 1u << (jwin >> 6);
      bestv = 3.4e38f;
      bests = 0;
#pragma unroll
      for (int s = 0; s < 32; ++s) {
        float v = (removed & (1u << s)) ? 3.4e38f : dv[s];
        if (v < bestv) { bestv = v; bests = s; }
      }
    }
  }
}

// ---------------- per-row edge features + 48x416 @ 416x128 bf16 MFMA GEMM ----------------
__global__ __launch_bounds__(256) void edge_kernel(const float* __restrict__ atoms5,
                                                   const u16* __restrict__ wt,
                                                   const int* __restrict__ eidx,
                                                   const float* __restrict__ dtop,
                                                   const int* __restrict__ Ridx,
                                                   const int* __restrict__ chains,
                                                   const float* __restrict__ Wpos,
                                                   const float* __restrict__ bpos,
                                                   const float* __restrict__ bedge,
                                                   float* __restrict__ Eout) {
  __shared__ u16 feat[KTOP * LROW];
  __shared__ float atomsJ[KTOP][15];
  __shared__ float atomsI[15];
  __shared__ int jbuf[KTOP];

  int row = blockIdx.x;
  int b = row >> 11, i = row & (NN - 1);
  int t = threadIdx.x;

  if (t < KTOP) jbuf[t] = eidx[row * KTOP + t];
  if (t < 15) atomsI[t] = atoms5[(size_t)row * 15 + t];
  __syncthreads();

  if (t < KTOP * 5) {
    int k = t / 5, a = t % 5;
    int j = jbuf[k];
    const float* src = atoms5 + ((size_t)(b * NN + j) * 15 + a * 3);
    atomsJ[k][a * 3 + 0] = src[0];
    atomsJ[k][a * 3 + 1] = src[1];
    atomsJ[k][a * 3 + 2] = src[2];
  }
  __syncthreads();

  // positional features (cols 0..15) + RBF of D_neighbors (cols 16..31)
  if (t < KTOP) {
    int k = t, j = jbuf[k];
    int Ri = Ridx[b * NN + i], Rj = Ridx[b * NN + j];
    int same = (chains[b * NN + i] == chains[b * NN + j]);
    int off = Ri - Rj + 32;
    off = off < 0 ? 0 : (off > 64 ? 64 : off);
    int drow = same ? off : 65;
#pragma unroll
    for (int r = 0; r < 16; ++r)
      feat[k * LROW + r] = bf16u(Wpos[drow * 16 + r] + bpos[r]);
    float D = dtop[row * KTOP + k];
#pragma unroll
    for (int r = 0; r < 16; ++r) {
      float mu = 2.0f + (20.0f * r) / 15.0f;
      float tt = (D - mu) * 0.8f;
      feat[k * LROW + 16 + r] = bf16u(__expf(-tt * tt));
    }
  }
  // remaining 24 atom-pair RBF blocks
  if (t < KTOP * 5) {
    int k = t / 5, g = t % 5;
    for (int p = 1 + g; p < 25; p += 5) {
      int a = cPA[p], b2 = cPB[p];
      float dx = atomsI[a * 3 + 0] - atomsJ[k][b2 * 3 + 0];
      float dy = atomsI[a * 3 + 1] - atomsJ[k][b2 * 3 + 1];
      float dz = atomsI[a * 3 + 2] - atomsJ[k][b2 * 3 + 2];
      float D = sqrtf(dx * dx + dy * dy + dz * dz + 1e-6f);
#pragma unroll
      for (int r = 0; r < 16; ++r) {
        float mu = 2.0f + (20.0f * r) / 15.0f;
        float tt = (D - mu) * 0.8f;
        feat[k * LROW + 16 + p * 16 + r] = bf16u(__expf(-tt * tt));
      }
    }
  }
  __syncthreads();

  // GEMM: (48 x 416) @ (416 x 128) with mfma 16x16x32 bf16. 4 waves x 32 cols.
  int w = t >> 6, lane = t & 63;
  int lr = lane & 15, lg = lane >> 4;
  f32x4 acc[3][2] = {};
  for (int kc = 0; kc < 13; ++kc) {
    s8v afrag[3];
#pragma unroll
    for (int mt = 0; mt < 3; ++mt)
      afrag[mt] = *reinterpret_cast<const s8v*>(&feat[(mt * 16 + lr) * LROW + kc * 32 + lg * 8]);
#pragma unroll
    for (int nt = 0; nt < 2; ++nt) {
      int col = w * 32 + nt * 16 + lr;
      s8v bfrag = *reinterpret_cast<const s8v*>(&wt[(size_t)col * EIN + kc * 32 + lg * 8]);
#pragma unroll
      for (int mt = 0; mt < 3; ++mt)
        acc[mt][nt] = __builtin_amdgcn_mfma_f32_16x16x32_bf16(afrag[mt], bfrag, acc[mt][nt], 0, 0, 0);
    }
  }
#pragma unroll
  for (int nt = 0; nt < 2; ++nt) {
    int col = w * 32 + nt * 16 + lr;
    float bias = bedge[col];
#pragma unroll
    for (int mt = 0; mt < 3; ++mt) {
#pragma unroll
      for (int q = 0; q < 4; ++q) {
        int m = mt * 16 + lg * 4 + q;
        Eout[((size_t)row * KTOP + m) * EF + col] = acc[mt][nt][q] + bias;
      }
    }
  }
}

extern "C" void kernel_launch(void* const* d_in, const int* in_sizes, int n_in,
                              void* d_out, int out_size, void* d_ws, size_t ws_size,
                              hipStream_t stream) {
  const float* X = (const float*)d_in[0];
  const float* mask = (const float*)d_in[1];
  const int* Ridx = (const int*)d_in[2];
  const int* chains = (const int*)d_in[3];
  const float* Wpos = (const float*)d_in[4];
  const float* bpos = (const float*)d_in[5];
  const float* Wedge = (const float*)d_in[6];
  const float* bedge = (const float*)d_in[7];

  float* Eout = (float*)d_out;
  float* EidxF = Eout + (size_t)BN * KTOP * EF;

  float* atoms5 = (float*)d_ws;
  float* capack = atoms5 + (size_t)BN * 15;
  u16* wt = (u16*)(capack + (size_t)BN * 3);
  int* eidx = (int*)(wt + (size_t)EIN * EF);
  float* dtop = (float*)(eidx + (size_t)BN * KTOP);

  int prep_threads = EIN * EF + BN;
  prep_kernel<<<(prep_threads + 255) / 256, 256, 0, stream>>>(X, Wedge, atoms5, capack, wt);
  topk_kernel<<<BN, 64, 0, stream>>>(capack, mask, eidx, dtop, EidxF);
  edge_kernel<<<BN, 256, 0, stream>>>(atoms5, wt, eidx, dtop, Ridx, chains, Wpos, bpos, bedge, Eout);
}

// Round 2
// 100.324 us; speedup vs baseline: 1.6490x; 1.6490x over previous
//
#include <hip/hip_runtime.h>
#include <hip/hip_bf16.h>
#include <stdint.h>

#define BB   2
#define NN   2048
#define BN   (BB*NN)
#define KTOP 48
#define EIN  416
#define EF   128
#define LROW 424   // padded feature row length in ushorts

typedef __attribute__((ext_vector_type(8))) short s8v;
typedef __attribute__((ext_vector_type(4))) float f32x4;
typedef unsigned short u16;
typedef unsigned int u32;
typedef unsigned long long u64;

__device__ __constant__ int cPA[25] = {1,0,2,3,4,1,1,1,1,0,0,0,4,4,3,0,2,3,4,2,3,4,2,3,2};
__device__ __constant__ int cPB[25] = {1,0,2,3,4,0,2,3,4,2,3,4,2,3,2,1,1,1,1,0,0,0,4,4,3};

__device__ __forceinline__ u16 bf16u(float x) {
  __hip_bfloat16 h = __float2bfloat16(x);
  return *reinterpret_cast<u16*>(&h);
}

// ---------------- prep: atoms5 (N,Ca,C,O,Cb), packed Ca, W_edge^T in bf16 ----------------
__global__ __launch_bounds__(256) void prep_kernel(const float* __restrict__ X,
                                                   const float* __restrict__ W_edge,
                                                   float* __restrict__ atoms5,
                                                   float* __restrict__ capack,
                                                   u16* __restrict__ wt) {
  int tid = blockIdx.x * 256 + threadIdx.x;
  if (tid < EIN * EF) {
    int n = tid & (EF - 1), kk = tid >> 7;
    wt[(size_t)n * EIN + kk] = bf16u(W_edge[tid]);
  } else if (tid < EIN * EF + BN) {
    int idx = tid - EIN * EF;
    const float* x = X + (size_t)idx * 12;
    float Nx = x[0], Ny = x[1], Nz = x[2];
    float Cax = x[3], Cay = x[4], Caz = x[5];
    float Cx = x[6], Cy = x[7], Cz = x[8];
    float Ox = x[9], Oy = x[10], Oz = x[11];
    float bx = Cax - Nx, by = Cay - Ny, bz = Caz - Nz;
    float cx = Cx - Cax, cy = Cy - Cay, cz = Cz - Caz;
    float ax = by * cz - bz * cy;
    float ay = bz * cx - bx * cz;
    float az = bx * cy - by * cx;
    float Cbx = -0.58273431f * ax + 0.56802827f * bx - 0.54067466f * cx + Cax;
    float Cby = -0.58273431f * ay + 0.56802827f * by - 0.54067466f * cy + Cay;
    float Cbz = -0.58273431f * az + 0.56802827f * bz - 0.54067466f * cz + Caz;
    float* o = atoms5 + (size_t)idx * 15;
    o[0] = Nx;  o[1] = Ny;  o[2] = Nz;
    o[3] = Cax; o[4] = Cay; o[5] = Caz;
    o[6] = Cx;  o[7] = Cy;  o[8] = Cz;
    o[9] = Ox;  o[10] = Oy; o[11] = Oz;
    o[12] = Cbx; o[13] = Cby; o[14] = Cbz;
    capack[idx * 3 + 0] = Cax;
    capack[idx * 3 + 1] = Cay;
    capack[idx * 3 + 2] = Caz;
  }
}

// exclusive block scan over 256 threads (trailing barrier makes scanw reusable)
__device__ __forceinline__ u32 blockExclScan(u32 v, u32* scanw, int t) {
  int lane = t & 63, w = t >> 6;
  u32 inc = v;
#pragma unroll
  for (int off = 1; off < 64; off <<= 1) {
    u32 o = __shfl_up(inc, off);
    if (lane >= off) inc += o;
  }
  if (lane == 63) scanw[w] = inc;
  __syncthreads();
  u32 base = 0;
  for (int ww = 0; ww < w; ++ww) base += scanw[ww];
  __syncthreads();
  return base + inc - v;
}

// one radix round: histogram keys matching prefix, find bin containing rank r.
// writes selinfo[0]=selected bin, selinfo[1]=new rank within bin. Ends with barrier.
template<int NB, bool CHKPREF>
__device__ __forceinline__ void radix_round(u32* hist, u32* scanw, u32* selinfo, int t,
                                            const u32* kv, u32 pref, int prefShift,
                                            int binShift, u32 binMask, u32 r) {
  const int PB = NB / 256;
  for (int q = 0; q < PB; ++q) hist[t * PB + q] = 0;
  __syncthreads();
#pragma unroll
  for (int s = 0; s < 8; ++s) {
    bool ok = (!CHKPREF) || ((kv[s] >> prefShift) == pref);
    if (ok) atomicAdd(&hist[(kv[s] >> binShift) & binMask], 1u);
  }
  __syncthreads();
  u32 loc[PB];
  u32 sum = 0;
  for (int q = 0; q < PB; ++q) { loc[q] = hist[t * PB + q]; sum += loc[q]; }
  int lane = t & 63, w = t >> 6;
  u32 inc = sum;
#pragma unroll
  for (int off = 1; off < 64; off <<= 1) {
    u32 o = __shfl_up(inc, off);
    if (lane >= off) inc += o;
  }
  if (lane == 63) scanw[w] = inc;
  __syncthreads();
  u32 base = 0;
  for (int ww = 0; ww < w; ++ww) base += scanw[ww];
  u32 c = base + inc - sum;
  for (int q = 0; q < PB; ++q) {
    u32 nc = c + loc[q];
    if (c < r && r <= nc) { selinfo[0] = (u32)(t * PB + q); selinfo[1] = r - c; }
    c = nc;
  }
  __syncthreads();
}

// ---------------- top-48 per row: 256 threads/row, exact radix select ----------------
__global__ __launch_bounds__(256) void topk_kernel(const float* __restrict__ capack,
                                                   const float* __restrict__ mask,
                                                   int* __restrict__ eidx,
                                                   float* __restrict__ dtop,
                                                   float* __restrict__ eidx_f) {
  __shared__ u32 hist[4096];
  __shared__ u32 scanw[4];
  __shared__ u32 selinfo[2];
  __shared__ float redf[4];
  __shared__ u64 win[64];

  int row = blockIdx.x;
  int b = row >> 11, i = row & (NN - 1);
  int t = threadIdx.x, lane = t & 63, w = t >> 6;
  const float* cab = capack + (size_t)b * NN * 3;
  const float* mrow = mask + (size_t)b * NN;
  float cix = cab[i * 3 + 0], ciy = cab[i * 3 + 1], ciz = cab[i * 3 + 2];
  float mi = mrow[i];

  // distances for candidates j = t*8 + s  (thread-contiguous: j order == (t,s) order)
  float dvv[8], m2v[8];
  float lmax = 0.f;
#pragma unroll
  for (int s = 0; s < 8; ++s) {
    int j = t * 8 + s;
    float dx = cix - cab[j * 3 + 0];
    float dy = ciy - cab[j * 3 + 1];
    float dz = ciz - cab[j * 3 + 2];
    float d = sqrtf(dx * dx + dy * dy + dz * dz + 1e-6f);
    float m2 = mi * mrow[j];
    float D = m2 * d;
    dvv[s] = D; m2v[s] = m2;
    lmax = fmaxf(lmax, D);
  }
#pragma unroll
  for (int off = 32; off >= 1; off >>= 1) lmax = fmaxf(lmax, __shfl_xor(lmax, off));
  if (lane == 0) redf[w] = lmax;
  __syncthreads();
  float rmax = fmaxf(fmaxf(redf[0], redf[1]), fmaxf(redf[2], redf[3]));

  u32 kv[8];
#pragma unroll
  for (int s = 0; s < 8; ++s)
    kv[s] = __float_as_uint(dvv[s] + (1.0f - m2v[s]) * rmax);  // D>=0 -> monotone bits

  // exact 48th-smallest key via 3 radix rounds (12 + 10 + 10 bits)
  u32 r = KTOP;
  radix_round<4096, false>(hist, scanw, selinfo, t, kv, 0, 0, 20, 0xFFFu, r);
  u32 sel1 = selinfo[0]; r = selinfo[1];
  radix_round<1024, true>(hist, scanw, selinfo, t, kv, sel1, 20, 10, 0x3FFu, r);
  u32 sel2 = selinfo[0]; r = selinfo[1];
  u32 pref12 = (sel1 << 10) | sel2;
  radix_round<1024, true>(hist, scanw, selinfo, t, kv, pref12, 10, 0, 0x3FFu, r);
  u32 sel3 = selinfo[0];
  u32 takeEq = selinfo[1];
  u32 T = (sel1 << 20) | (sel2 << 10) | sel3;

  // winners: all keys < T, plus first takeEq keys == T in index order
  u32 lcnt = 0, ecnt = 0;
#pragma unroll
  for (int s = 0; s < 8; ++s) { lcnt += (kv[s] < T); ecnt += (kv[s] == T); }
  u32 ebase = blockExclScan(ecnt, scanw, t);
  u32 taken = 0;
  if (ebase < takeEq) { u32 room = takeEq - ebase; taken = room < ecnt ? room : ecnt; }
  u32 wbase = blockExclScan(lcnt + taken, scanw, t);
  u32 slot = wbase, tleft = taken;
#pragma unroll
  for (int s = 0; s < 8; ++s) {
    u32 j = (u32)(t * 8 + s);
    if (kv[s] < T) {
      win[slot++] = ((u64)kv[s] << 32) | j;
    } else if (kv[s] == T && tleft) {
      win[slot++] = ((u64)kv[s] << 32) | j;
      tleft--;
    }
  }
  __syncthreads();

  // wave 0: bitonic sort 48 (padded to 64) by (key, index) ascending; write out
  if (w == 0) {
    u64 key = (lane < KTOP) ? win[lane] : ~0ull;
#pragma unroll
    for (int k = 2; k <= 64; k <<= 1) {
#pragma unroll
      for (int jj = k >> 1; jj >= 1; jj >>= 1) {
        u64 p = __shfl_xor(key, jj);
        bool lowerl = (lane & jj) == 0;
        bool asc = (lane & k) == 0;
        u64 mn = p < key ? p : key;
        u64 mx = p < key ? key : p;
        key = (lowerl == asc) ? mn : mx;
      }
    }
    if (lane < KTOP) {
      u32 j = (u32)(key & 0xffffffffu);
      eidx[row * KTOP + lane] = (int)j;
      eidx_f[row * KTOP + lane] = (float)j;
      dtop[row * KTOP + lane] = __uint_as_float((u32)(key >> 32));
    }
  }
}

// ---------------- per-row edge features + 48x416 @ 416x128 bf16 MFMA GEMM ----------------
__global__ __launch_bounds__(256) void edge_kernel(const float* __restrict__ atoms5,
                                                   const u16* __restrict__ wt,
                                                   const int* __restrict__ eidx,
                                                   const float* __restrict__ dtop,
                                                   const int* __restrict__ Ridx,
                                                   const int* __restrict__ chains,
                                                   const float* __restrict__ Wpos,
                                                   const float* __restrict__ bpos,
                                                   const float* __restrict__ bedge,
                                                   float* __restrict__ Eout) {
  __shared__ u16 feat[KTOP * LROW];
  __shared__ float atomsJ[KTOP][15];
  __shared__ float atomsI[15];
  __shared__ int jbuf[KTOP];

  int row = blockIdx.x;
  int b = row >> 11, i = row & (NN - 1);
  int t = threadIdx.x;

  if (t < KTOP) jbuf[t] = eidx[row * KTOP + t];
  if (t < 15) atomsI[t] = atoms5[(size_t)row * 15 + t];
  __syncthreads();

  if (t < KTOP * 5) {
    int k = t / 5, a = t % 5;
    int j = jbuf[k];
    const float* src = atoms5 + ((size_t)(b * NN + j) * 15 + a * 3);
    atomsJ[k][a * 3 + 0] = src[0];
    atomsJ[k][a * 3 + 1] = src[1];
    atomsJ[k][a * 3 + 2] = src[2];
  }
  __syncthreads();

  if (t < KTOP) {
    int k = t, j = jbuf[k];
    int Ri = Ridx[b * NN + i], Rj = Ridx[b * NN + j];
    int same = (chains[b * NN + i] == chains[b * NN + j]);
    int off = Ri - Rj + 32;
    off = off < 0 ? 0 : (off > 64 ? 64 : off);
    int drow = same ? off : 65;
#pragma unroll
    for (int r = 0; r < 16; ++r)
      feat[k * LROW + r] = bf16u(Wpos[drow * 16 + r] + bpos[r]);
    float D = dtop[row * KTOP + k];
#pragma unroll
    for (int r = 0; r < 16; ++r) {
      float mu = 2.0f + (20.0f * r) / 15.0f;
      float tt = (D - mu) * 0.8f;
      feat[k * LROW + 16 + r] = bf16u(__expf(-tt * tt));
    }
  }
  if (t < KTOP * 5) {
    int k = t / 5, g = t % 5;
    for (int p = 1 + g; p < 25; p += 5) {
      int a = cPA[p], b2 = cPB[p];
      float dx = atomsI[a * 3 + 0] - atomsJ[k][b2 * 3 + 0];
      float dy = atomsI[a * 3 + 1] - atomsJ[k][b2 * 3 + 1];
      float dz = atomsI[a * 3 + 2] - atomsJ[k][b2 * 3 + 2];
      float D = sqrtf(dx * dx + dy * dy + dz * dz + 1e-6f);
#pragma unroll
      for (int r = 0; r < 16; ++r) {
        float mu = 2.0f + (20.0f * r) / 15.0f;
        float tt = (D - mu) * 0.8f;
        feat[k * LROW + 16 + p * 16 + r] = bf16u(__expf(-tt * tt));
      }
    }
  }
  __syncthreads();

  int w = t >> 6, lane = t & 63;
  int lr = lane & 15, lg = lane >> 4;
  f32x4 acc[3][2] = {};
  for (int kc = 0; kc < 13; ++kc) {
    s8v afrag[3];
#pragma unroll
    for (int mt = 0; mt < 3; ++mt)
      afrag[mt] = *reinterpret_cast<const s8v*>(&feat[(mt * 16 + lr) * LROW + kc * 32 + lg * 8]);
#pragma unroll
    for (int nt = 0; nt < 2; ++nt) {
      int col = w * 32 + nt * 16 + lr;
      s8v bfrag = *reinterpret_cast<const s8v*>(&wt[(size_t)col * EIN + kc * 32 + lg * 8]);
#pragma unroll
      for (int mt = 0; mt < 3; ++mt)
        acc[mt][nt] = __builtin_amdgcn_mfma_f32_16x16x32_bf16(afrag[mt], bfrag, acc[mt][nt], 0, 0, 0);
    }
  }
#pragma unroll
  for (int nt = 0; nt < 2; ++nt) {
    int col = w * 32 + nt * 16 + lr;
    float bias = bedge[col];
#pragma unroll
    for (int mt = 0; mt < 3; ++mt) {
#pragma unroll
      for (int q = 0; q < 4; ++q) {
        int m = mt * 16 + lg * 4 + q;
        Eout[((size_t)row * KTOP + m) * EF + col] = acc[mt][nt][q] + bias;
      }
    }
  }
}

extern "C" void kernel_launch(void* const* d_in, const int* in_sizes, int n_in,
                              void* d_out, int out_size, void* d_ws, size_t ws_size,
                              hipStream_t stream) {
  const float* X = (const float*)d_in[0];
  const float* mask = (const float*)d_in[1];
  const int* Ridx = (const int*)d_in[2];
  const int* chains = (const int*)d_in[3];
  const float* Wpos = (const float*)d_in[4];
  const float* bpos = (const float*)d_in[5];
  const float* Wedge = (const float*)d_in[6];
  const float* bedge = (const float*)d_in[7];

  float* Eout = (float*)d_out;
  float* EidxF = Eout + (size_t)BN * KTOP * EF;

  float* atoms5 = (float*)d_ws;
  float* capack = atoms5 + (size_t)BN * 15;
  u16* wt = (u16*)(capack + (size_t)BN * 3);
  int* eidx = (int*)(wt + (size_t)EIN * EF);
  float* dtop = (float*)(eidx + (size_t)BN * KTOP);

  int prep_threads = EIN * EF + BN;
  prep_kernel<<<(prep_threads + 255) / 256, 256, 0, stream>>>(X, Wedge, atoms5, capack, wt);
  topk_kernel<<<BN, 256, 0, stream>>>(capack, mask, eidx, dtop, EidxF);
  edge_kernel<<<BN, 256, 0, stream>>>(atoms5, wt, eidx, dtop, Ridx, chains, Wpos, bpos, bedge, Eout);
}

// Round 3
// 96.437 us; speedup vs baseline: 1.7154x; 1.0403x over previous
//
#include <hip/hip_runtime.h>
#include <hip/hip_bf16.h>
#include <stdint.h>

#define BB   2
#define NN   2048
#define BN   (BB*NN)
#define KTOP 48
#define EIN  416
#define EF   128
#define LROW 424   // padded feature row (u16): 848B, 16B-aligned, 2-way-free on reads
#define SROW 132   // f32 staging row pad

typedef __attribute__((ext_vector_type(8))) short s8v;
typedef __attribute__((ext_vector_type(4))) float f32x4;
typedef __attribute__((ext_vector_type(4))) unsigned int u32x4;
typedef unsigned short u16;
typedef unsigned int u32;
typedef unsigned long long u64;

__device__ __constant__ int cPA[25] = {1,0,2,3,4,1,1,1,1,0,0,0,4,4,3,0,2,3,4,2,3,4,2,3,2};
__device__ __constant__ int cPB[25] = {1,0,2,3,4,0,2,3,4,2,3,4,2,3,2,1,1,1,1,0,0,0,4,4,3};

__device__ __forceinline__ u16 bf16u(float x) {
  __hip_bfloat16 h = __float2bfloat16(x);
  return *reinterpret_cast<u16*>(&h);
}
__device__ __forceinline__ u32 pack2(float lo, float hi) {
  return (u32)bf16u(lo) | ((u32)bf16u(hi) << 16);
}

// ---------------- prep: padded atoms [BN][5][4], Ca pack [BN][4], W_edge MFMA-tiled bf16 ----
__global__ __launch_bounds__(256) void prep_kernel(const float* __restrict__ X,
                                                   const float* __restrict__ W_edge,
                                                   float* __restrict__ atoms5p,
                                                   float* __restrict__ capack4,
                                                   u16* __restrict__ wtf) {
  int tid = blockIdx.x * 256 + threadIdx.x;
  if (tid < EIN * EF) {
    int k = tid >> 7, n = tid & 127;
    // fragment-order tile: wtf[(k>>3)*1024 + n*8 + (k&7)]
    wtf[((size_t)(k >> 3)) * 1024 + n * 8 + (k & 7)] = bf16u(W_edge[tid]);
  } else if (tid < EIN * EF + BN) {
    int idx = tid - EIN * EF;
    const float* x = X + (size_t)idx * 12;
    float Nx = x[0], Ny = x[1], Nz = x[2];
    float Cax = x[3], Cay = x[4], Caz = x[5];
    float Cx = x[6], Cy = x[7], Cz = x[8];
    float Ox = x[9], Oy = x[10], Oz = x[11];
    float bx = Cax - Nx, by = Cay - Ny, bz = Caz - Nz;
    float cx = Cx - Cax, cy = Cy - Cay, cz = Cz - Caz;
    float ax = by * cz - bz * cy;
    float ay = bz * cx - bx * cz;
    float az = bx * cy - by * cx;
    float Cbx = -0.58273431f * ax + 0.56802827f * bx - 0.54067466f * cx + Cax;
    float Cby = -0.58273431f * ay + 0.56802827f * by - 0.54067466f * cy + Cay;
    float Cbz = -0.58273431f * az + 0.56802827f * bz - 0.54067466f * cz + Caz;
    f32x4* o = (f32x4*)(atoms5p + (size_t)idx * 20);
    o[0] = (f32x4){Nx, Ny, Nz, 0.f};
    o[1] = (f32x4){Cax, Cay, Caz, 0.f};
    o[2] = (f32x4){Cx, Cy, Cz, 0.f};
    o[3] = (f32x4){Ox, Oy, Oz, 0.f};
    o[4] = (f32x4){Cbx, Cby, Cbz, 0.f};
    *(f32x4*)(capack4 + (size_t)idx * 4) = (f32x4){Cax, Cay, Caz, 0.f};
  }
}

// exclusive block scan over 256 threads
__device__ __forceinline__ u32 blockExclScan(u32 v, u32* scanw, int t) {
  int lane = t & 63, w = t >> 6;
  u32 inc = v;
#pragma unroll
  for (int off = 1; off < 64; off <<= 1) {
    u32 o = __shfl_up(inc, off);
    if (lane >= off) inc += o;
  }
  if (lane == 63) scanw[w] = inc;
  __syncthreads();
  u32 base = 0;
  for (int ww = 0; ww < w; ++ww) base += scanw[ww];
  __syncthreads();
  return base + inc - v;
}

template<int NB, bool CHKPREF>
__device__ __forceinline__ void radix_round(u32* hist, u32* scanw, u32* selinfo, int t,
                                            const u32* kv, u32 pref, int prefShift,
                                            int binShift, u32 binMask, u32 r) {
  const int PB = NB / 256;
#pragma unroll
  for (int q = 0; q < PB / 4; ++q)
    *(u32x4*)&hist[t * PB + q * 4] = (u32x4){0, 0, 0, 0};
  __syncthreads();
#pragma unroll
  for (int s = 0; s < 8; ++s) {
    bool ok = (!CHKPREF) || ((kv[s] >> prefShift) == pref);
    if (ok) atomicAdd(&hist[(kv[s] >> binShift) & binMask], 1u);
  }
  __syncthreads();
  u32 loc[PB];
  u32 sum = 0;
#pragma unroll
  for (int q = 0; q < PB / 4; ++q) {
    u32x4 lv = *(u32x4*)&hist[t * PB + q * 4];
    loc[q * 4 + 0] = lv.x; loc[q * 4 + 1] = lv.y;
    loc[q * 4 + 2] = lv.z; loc[q * 4 + 3] = lv.w;
    sum += lv.x + lv.y + lv.z + lv.w;
  }
  int lane = t & 63, w = t >> 6;
  u32 inc = sum;
#pragma unroll
  for (int off = 1; off < 64; off <<= 1) {
    u32 o = __shfl_up(inc, off);
    if (lane >= off) inc += o;
  }
  if (lane == 63) scanw[w] = inc;
  __syncthreads();
  u32 base = 0;
  for (int ww = 0; ww < w; ++ww) base += scanw[ww];
  u32 c = base + inc - sum;
#pragma unroll
  for (int q = 0; q < PB; ++q) {
    u32 nc = c + loc[q];
    if (c < r && r <= nc) { selinfo[0] = (u32)(t * PB + q); selinfo[1] = r - c; }
    c = nc;
  }
  __syncthreads();
}

// ---------------- top-48 per row: exact radix select ----------------
__global__ __launch_bounds__(256) void topk_kernel(const float* __restrict__ capack4,
                                                   const float* __restrict__ mask,
                                                   float* __restrict__ dtop,
                                                   float* __restrict__ eidx_f) {
  __shared__ u32 hist[4096];
  __shared__ u32 scanw[4];
  __shared__ u32 selinfo[2];
  __shared__ float redf[4];
  __shared__ u64 win[64];

  int row = blockIdx.x;
  int b = row >> 11, i = row & (NN - 1);
  int t = threadIdx.x, lane = t & 63, w = t >> 6;
  const float* cab4 = capack4 + (size_t)b * NN * 4;
  const float* mrow = mask + (size_t)b * NN;
  f32x4 ci = *(const f32x4*)&cab4[(size_t)i * 4];
  float mi = mrow[i];
  f32x4 mk0 = *(const f32x4*)&mrow[t * 8];
  f32x4 mk1 = *(const f32x4*)&mrow[t * 8 + 4];

  float dvv[8], m2v[8];
  float lmax = 0.f;
#pragma unroll
  for (int s = 0; s < 8; ++s) {
    f32x4 cj = *(const f32x4*)&cab4[(size_t)(t * 8 + s) * 4];
    float dx = ci.x - cj.x, dy = ci.y - cj.y, dz = ci.z - cj.z;
    float d = sqrtf(dx * dx + dy * dy + dz * dz + 1e-6f);
    float mj = (s < 4) ? mk0[s] : mk1[s - 4];
    float m2 = mi * mj;
    float D = m2 * d;
    dvv[s] = D; m2v[s] = m2;
    lmax = fmaxf(lmax, D);
  }
#pragma unroll
  for (int off = 32; off >= 1; off >>= 1) lmax = fmaxf(lmax, __shfl_xor(lmax, off));
  if (lane == 0) redf[w] = lmax;
  __syncthreads();
  float rmax = fmaxf(fmaxf(redf[0], redf[1]), fmaxf(redf[2], redf[3]));

  u32 kv[8];
#pragma unroll
  for (int s = 0; s < 8; ++s)
    kv[s] = __float_as_uint(dvv[s] + (1.0f - m2v[s]) * rmax);

  u32 r = KTOP;
  radix_round<4096, false>(hist, scanw, selinfo, t, kv, 0, 0, 20, 0xFFFu, r);
  u32 sel1 = selinfo[0]; r = selinfo[1];
  radix_round<1024, true>(hist, scanw, selinfo, t, kv, sel1, 20, 10, 0x3FFu, r);
  u32 sel2 = selinfo[0]; r = selinfo[1];
  u32 pref12 = (sel1 << 10) | sel2;
  radix_round<1024, true>(hist, scanw, selinfo, t, kv, pref12, 10, 0, 0x3FFu, r);
  u32 sel3 = selinfo[0];
  u32 takeEq = selinfo[1];
  u32 T = (sel1 << 20) | (sel2 << 10) | sel3;

  u32 lcnt = 0, ecnt = 0;
#pragma unroll
  for (int s = 0; s < 8; ++s) { lcnt += (kv[s] < T); ecnt += (kv[s] == T); }
  u32 ebase = blockExclScan(ecnt, scanw, t);
  u32 taken = 0;
  if (ebase < takeEq) { u32 room = takeEq - ebase; taken = room < ecnt ? room : ecnt; }
  u32 wbase = blockExclScan(lcnt + taken, scanw, t);
  u32 slot = wbase, tleft = taken;
#pragma unroll
  for (int s = 0; s < 8; ++s) {
    u32 j = (u32)(t * 8 + s);
    if (kv[s] < T) {
      win[slot++] = ((u64)kv[s] << 32) | j;
    } else if (kv[s] == T && tleft) {
      win[slot++] = ((u64)kv[s] << 32) | j;
      tleft--;
    }
  }
  __syncthreads();

  if (w == 0) {
    u64 key = (lane < KTOP) ? win[lane] : ~0ull;
#pragma unroll
    for (int k = 2; k <= 64; k <<= 1) {
#pragma unroll
      for (int jj = k >> 1; jj >= 1; jj >>= 1) {
        u64 p = __shfl_xor(key, jj);
        bool lowerl = (lane & jj) == 0;
        bool asc = (lane & k) == 0;
        u64 mn = p < key ? p : key;
        u64 mx = p < key ? key : p;
        key = (lowerl == asc) ? mn : mx;
      }
    }
    if (lane < KTOP) {
      u32 j = (u32)(key & 0xffffffffu);
      eidx_f[row * KTOP + lane] = (float)j;
      dtop[row * KTOP + lane] = __uint_as_float((u32)(key >> 32));
    }
  }
}

// ---------------- edge features + 48x416 @ 416x128 bf16 MFMA GEMM ----------------
__global__ __launch_bounds__(256, 4) void edge_kernel(const float* __restrict__ atoms5p,
                                                      const u16* __restrict__ wtf,
                                                      const float* __restrict__ eidx_f,
                                                      const float* __restrict__ dtop,
                                                      const int* __restrict__ Ridx,
                                                      const int* __restrict__ chains,
                                                      const float* __restrict__ Wpos,
                                                      const float* __restrict__ bpos,
                                                      const float* __restrict__ bedge,
                                                      float* __restrict__ Eout) {
  __shared__ __align__(16) u16 featsm[KTOP * LROW];   // 40704 B; aliased as f32 staging later
  __shared__ int jbuf[KTOP];

  int row = blockIdx.x;
  int b = row >> 11, i = row & (NN - 1);
  int t = threadIdx.x;

  if (t < KTOP) jbuf[t] = (int)eidx_f[row * KTOP + t];
  __syncthreads();

  const float* atomsB = atoms5p + (size_t)b * NN * 20;

#pragma unroll
  for (int q = 0; q < 5; ++q) {
    int e = t + q * 256;
    if (e < KTOP * 26) {
      int k = e / 26;
      int c = e - k * 26;
      int j = jbuf[k];
      u32 pk[8];
      if (c == 0) {
        int Ri = Ridx[b * NN + i], Rj = Ridx[b * NN + j];
        int same = (chains[b * NN + i] == chains[b * NN + j]);
        int off = Ri - Rj + 32;
        off = off < 0 ? 0 : (off > 64 ? 64 : off);
        int drow = same ? off : 65;
        const float* wr = Wpos + drow * 16;
#pragma unroll
        for (int h = 0; h < 4; ++h) {
          f32x4 wv = *(const f32x4*)&wr[h * 4];
          f32x4 bv = *(const f32x4*)&bpos[h * 4];
          pk[h * 2 + 0] = pack2(wv.x + bv.x, wv.y + bv.y);
          pk[h * 2 + 1] = pack2(wv.z + bv.z, wv.w + bv.w);
        }
      } else {
        float D;
        if (c == 1) {
          D = dtop[row * KTOP + k];
        } else {
          int p = c - 1;
          f32x4 I = *(const f32x4*)&atomsB[(size_t)i * 20 + cPA[p] * 4];
          f32x4 J = *(const f32x4*)&atomsB[(size_t)j * 20 + cPB[p] * 4];
          float dx = I.x - J.x, dy = I.y - J.y, dz = I.z - J.z;
          D = sqrtf(dx * dx + dy * dy + dz * dz + 1e-6f);
        }
        // RBF recurrence: v_{r+1} = v_r * g_r, g_{r+1} = g_r * exp(-2*delta^2)
        float Dc = fminf(D, 40.0f);
        float t0 = (Dc - 2.0f) * 0.8f;
        float v = __expf(-t0 * t0);
        float g = __expf(2.13333333f * t0 - 1.13777778f);
#pragma unroll
        for (int h = 0; h < 8; ++h) {
          float lo = v; v *= g; g *= 0.10273985f;
          float hi = v; v *= g; g *= 0.10273985f;
          pk[h] = pack2(lo, hi);
        }
      }
      u32x4* dst = (u32x4*)&featsm[k * LROW + c * 16];
      dst[0] = (u32x4){pk[0], pk[1], pk[2], pk[3]};
      dst[1] = (u32x4){pk[4], pk[5], pk[6], pk[7]};
    }
  }
  __syncthreads();

  // GEMM: (48 x 416) @ (416 x 128), 4 waves x 32 cols
  int w = t >> 6, lane = t & 63;
  int lr = lane & 15, lg = lane >> 4;
  f32x4 acc[3][2] = {};
  for (int kc = 0; kc < 13; ++kc) {
    s8v afrag[3];
#pragma unroll
    for (int mt = 0; mt < 3; ++mt)
      afrag[mt] = *reinterpret_cast<const s8v*>(&featsm[(mt * 16 + lr) * LROW + kc * 32 + lg * 8]);
#pragma unroll
    for (int nt = 0; nt < 2; ++nt) {
      int col = w * 32 + nt * 16 + lr;
      s8v bfrag = *reinterpret_cast<const s8v*>(&wtf[(size_t)(kc * 4 + lg) * 1024 + col * 8]);
#pragma unroll
      for (int mt = 0; mt < 3; ++mt)
        acc[mt][nt] = __builtin_amdgcn_mfma_f32_16x16x32_bf16(afrag[mt], bfrag, acc[mt][nt], 0, 0, 0);
    }
  }
  __syncthreads();   // all feat reads done; reuse LDS as f32 staging

  float* stage = (float*)featsm;  // 48 x SROW
  float bias0 = bedge[w * 32 + lr];
  float bias1 = bedge[w * 32 + 16 + lr];
#pragma unroll
  for (int nt = 0; nt < 2; ++nt) {
    float bias = nt ? bias1 : bias0;
    int col = w * 32 + nt * 16 + lr;
#pragma unroll
    for (int mt = 0; mt < 3; ++mt) {
#pragma unroll
      for (int qq = 0; qq < 4; ++qq) {
        int m = mt * 16 + lg * 4 + qq;
        stage[m * SROW + col] = acc[mt][nt][qq] + bias;
      }
    }
  }
  __syncthreads();

  float* orow = Eout + (size_t)row * KTOP * EF;
#pragma unroll
  for (int q2 = 0; q2 < 6; ++q2) {
    int o = t * 4 + q2 * 1024;
    int m = o >> 7, col = o & 127;
    f32x4 vv = *(f32x4*)&stage[m * SROW + col];
    *(f32x4*)&orow[m * EF + col] = vv;
  }
}

extern "C" void kernel_launch(void* const* d_in, const int* in_sizes, int n_in,
                              void* d_out, int out_size, void* d_ws, size_t ws_size,
                              hipStream_t stream) {
  const float* X = (const float*)d_in[0];
  const float* mask = (const float*)d_in[1];
  const int* Ridx = (const int*)d_in[2];
  const int* chains = (const int*)d_in[3];
  const float* Wpos = (const float*)d_in[4];
  const float* bpos = (const float*)d_in[5];
  const float* Wedge = (const float*)d_in[6];
  const float* bedge = (const float*)d_in[7];

  float* Eout = (float*)d_out;
  float* EidxF = Eout + (size_t)BN * KTOP * EF;

  u16* wtf = (u16*)d_ws;                                   // 53248 u16
  float* atoms5p = (float*)((char*)d_ws + 53248 * 2);      // BN*20 f32
  float* capack4 = atoms5p + (size_t)BN * 20;              // BN*4 f32
  float* dtop = capack4 + (size_t)BN * 4;                  // BN*48 f32

  prep_kernel<<<(EIN * EF + BN + 255) / 256, 256, 0, stream>>>(X, Wedge, atoms5p, capack4, wtf);
  topk_kernel<<<BN, 256, 0, stream>>>(capack4, mask, dtop, EidxF);
  edge_kernel<<<BN, 256, 0, stream>>>(atoms5p, wtf, EidxF, dtop, Ridx, chains, Wpos, bpos, bedge, Eout);
}